// Round 1
// baseline (464.369 us; speedup 1.0000x reference)
//
#include <hip/hip_runtime.h>
#include <stdint.h>

typedef __attribute__((ext_vector_type(8))) short bf16x8;   // 8 bf16 in 4 VGPRs
typedef __attribute__((ext_vector_type(4))) float f32x4;

#define DM   1024
#define TT   1024
#define NH   16
#define DKH  64
#define SPAN 512
#define S2   1024   // 2*SPAN
#define MT   4096   // 4*TT rows

__device__ __forceinline__ unsigned short f2b(float f) {
  unsigned int u = __builtin_bit_cast(unsigned int, f);
  u = (u + 0x7FFFu + ((u >> 16) & 1u)) >> 16;   // RTNE
  return (unsigned short)u;
}
__device__ __forceinline__ float b2f(unsigned short h) {
  unsigned int u = ((unsigned int)h) << 16;
  return __builtin_bit_cast(float, u);
}

// ---------------- f32 -> bf16 convert ----------------
__global__ void cvt_kernel(const float* __restrict__ in, unsigned short* __restrict__ out, int n) {
  int i = (blockIdx.x * blockDim.x + threadIdx.x) * 4;
  int stride = gridDim.x * blockDim.x * 4;
  for (; i < n; i += stride) {
    float4 v = *(const float4*)(in + i);
    ushort4 o;
    o.x = f2b(v.x); o.y = f2b(v.y); o.z = f2b(v.z); o.w = f2b(v.w);
    *(ushort4*)(out + i) = o;
  }
}

// ---------------- multi-z bf16 GEMM: C_z = (A_z(M,K) @ B_z(N,K)^T + bias_z) * alpha_z -------
// mode per z (4 bits in `modes`): 0 = f32 out, 1 = bf16 out, 2 = bf16 TRANSPOSED out C[col*M+row]
__global__ __launch_bounds__(256) void gemm_bt(
    const unsigned short* __restrict__ A, const unsigned short* __restrict__ B,
    const float* __restrict__ bias0, const float* __restrict__ bias1, const float* __restrict__ bias2,
    void* __restrict__ C,
    int M, int N, int K, int lda, int ldb, int ldc,
    long long sA, long long sB, long long sC,
    float a0, float a1, float a2, int modes)
{
  __shared__ unsigned short Al[128 * 72];
  __shared__ unsigned short Bl[128 * 72];
  const int t = threadIdx.x;
  const int w = t >> 6, l = t & 63;
  const int g = l >> 4, li = l & 15;
  const int wr = w >> 1, wc = w & 1;
  const int row0 = blockIdx.x * 128, col0 = blockIdx.y * 128;
  const int z = blockIdx.z;
  const unsigned short* Ab = A + (long long)z * sA;
  const unsigned short* Bb = B + (long long)z * sB;

  f32x4 acc[4][4];
#pragma unroll
  for (int m = 0; m < 4; m++)
#pragma unroll
    for (int n = 0; n < 4; n++) acc[m][n] = (f32x4){0.f, 0.f, 0.f, 0.f};

  for (int k0 = 0; k0 < K; k0 += 64) {
    __syncthreads();
#pragma unroll
    for (int i = 0; i < 4; i++) {
      int c = t + 256 * i;
      int r = c >> 3, c8 = (c & 7) * 8;
      *(bf16x8*)&Al[r * 72 + c8] = *(const bf16x8*)&Ab[(long long)(row0 + r) * lda + k0 + c8];
      *(bf16x8*)&Bl[r * 72 + c8] = *(const bf16x8*)&Bb[(long long)(col0 + r) * ldb + k0 + c8];
    }
    __syncthreads();
#pragma unroll
    for (int kk = 0; kk < 2; kk++) {
      bf16x8 af[4], bfr[4];
#pragma unroll
      for (int m = 0; m < 4; m++) af[m]  = *(bf16x8*)&Al[(wr * 64 + m * 16 + li) * 72 + kk * 32 + g * 8];
#pragma unroll
      for (int n = 0; n < 4; n++) bfr[n] = *(bf16x8*)&Bl[(wc * 64 + n * 16 + li) * 72 + kk * 32 + g * 8];
#pragma unroll
      for (int m = 0; m < 4; m++)
#pragma unroll
        for (int n = 0; n < 4; n++)
          acc[m][n] = __builtin_amdgcn_mfma_f32_16x16x32_bf16(af[m], bfr[n], acc[m][n], 0, 0, 0);
    }
  }

  const float alpha = z == 0 ? a0 : (z == 1 ? a1 : a2);
  const float* bias = z == 0 ? bias0 : (z == 1 ? bias1 : bias2);
  const int mode = (modes >> (4 * z)) & 15;
  const long long zoff = (long long)z * sC;

#pragma unroll
  for (int m = 0; m < 4; m++) {
    int row = row0 + wr * 64 + m * 16 + g * 4;
#pragma unroll
    for (int n = 0; n < 4; n++) {
      int col = col0 + wc * 64 + n * 16 + li;
      float bv = bias ? bias[col] : 0.0f;
      if (mode == 2) {
        // transposed bf16: 4 consecutive rows (k) -> one ushort4 along the fast axis
        ushort4 st;
        st.x = f2b((acc[m][n][0] + bv) * alpha);
        st.y = f2b((acc[m][n][1] + bv) * alpha);
        st.z = f2b((acc[m][n][2] + bv) * alpha);
        st.w = f2b((acc[m][n][3] + bv) * alpha);
        *(ushort4*)&((unsigned short*)C)[zoff + (long long)col * M + row] = st;
      } else {
#pragma unroll
        for (int r = 0; r < 4; r++) {
          float v = (acc[m][n][r] + bv) * alpha;
          long long idx = zoff + (long long)(row + r) * ldc + col;
          if (mode == 1) ((unsigned short*)C)[idx] = f2b(v);
          else           ((float*)C)[idx] = v;
        }
      }
    }
  }
}

// ---------------- fully fused disentangled attention ----------------
// grid (T/64, H, B); block 256 (4 waves x 16 q-rows each).
// score[q,k] = Qs.K + Qs.PK[s] + K.PQs[s], s = clamp(k-q+512, 0, 1023)
// (scale pre-folded into Q and PQ projections)
// Q/K fragments and V^T fragments are loaded directly from global (16 rows x 64B
// per instruction = fully-used cache lines); LDS holds only the PK/PQ windows,
// which are overwritten by the transposed c2p/p2c tiles, then P reuses rows 0..63.
__global__ __launch_bounds__(256, 3) void attn_fused(
    const unsigned short* __restrict__ Qb, const unsigned short* __restrict__ Kb,
    const unsigned short* __restrict__ VT,
    const unsigned short* __restrict__ PKb, const unsigned short* __restrict__ PQb,
    unsigned short* __restrict__ ctxb)
{
  __shared__ unsigned short PKw[128 * 72];  // PK window -> CtT[j][q] -> P rows 0..63
  __shared__ unsigned short PQw[128 * 72];  // PQ window -> PtT[j][k]

  const int t = threadIdx.x, w = t >> 6, l = t & 63, g = l >> 4, li = l & 15;
  const int q0 = blockIdx.x * 64;
  const int h = blockIdx.y, b = blockIdx.z;
  const long long qkbase = ((long long)b * TT) * DM + h * DKH;
  const long long vtb = (long long)(h * DKH) * MT + (long long)b * TT;  // + d*MT + k
  const int hbase = h * DKH;

  // Q fragments: direct global, once
  bf16x8 aq[2];
#pragma unroll
  for (int kk = 0; kk < 2; kk++)
    aq[kk] = *(const bf16x8*)&Qb[qkbase + (long long)(q0 + w * 16 + li) * DM + kk * 32 + g * 8];

  f32x4 o[4];
#pragma unroll
  for (int n = 0; n < 4; n++) o[n] = (f32x4){0.f, 0.f, 0.f, 0.f};
  float mrow[4], lrow[4];
#pragma unroll
  for (int r = 0; r < 4; r++) { mrow[r] = -1e30f; lrow[r] = 0.f; }

  for (int kt = 0; kt < TT / 64; kt++) {
    const int k0 = kt * 64;
    const int d0 = k0 - q0 + SPAN;                       // wave-uniform
    int w0 = d0 - 64;
    w0 = w0 < 0 ? 0 : (w0 > S2 - 128 ? S2 - 128 : w0);

    // K fragments early (global, independent of LDS) — latency hides under staging
    bf16x8 ak[2], bkf[2][4];
#pragma unroll
    for (int kk = 0; kk < 2; kk++) {
      ak[kk] = *(const bf16x8*)&Kb[qkbase + (long long)(k0 + w * 16 + li) * DM + kk * 32 + g * 8];
#pragma unroll
      for (int f = 0; f < 4; f++)
        bkf[kk][f] = *(const bf16x8*)&Kb[qkbase + (long long)(k0 + f * 16 + li) * DM + kk * 32 + g * 8];
    }

    __syncthreads();  // [A] prior tile fully done with PKw/PQw
    // stage PK / PQ windows (128 rows x 64 cols each)
#pragma unroll
    for (int i = 0; i < 4; i++) {
      int c = t + 256 * i;
      int jr = c >> 3, c8 = (c & 7) * 8;
      *(bf16x8*)&PKw[jr * 72 + c8] = *(const bf16x8*)&PKb[(long long)(w0 + jr) * DM + hbase + c8];
      *(bf16x8*)&PQw[jr * 72 + c8] = *(const bf16x8*)&PQb[(long long)(w0 + jr) * DM + hbase + c8];
    }
    __syncthreads();  // [B] windows visible

    // QK^T: 16 q-rows x 64 k-cols (Q pre-scaled)
    f32x4 sc[4];
#pragma unroll
    for (int f = 0; f < 4; f++) sc[f] = (f32x4){0.f, 0.f, 0.f, 0.f};
#pragma unroll
    for (int kk = 0; kk < 2; kk++)
#pragma unroll
      for (int f = 0; f < 4; f++)
        sc[f] = __builtin_amdgcn_mfma_f32_16x16x32_bf16(aq[kk], bkf[kk][f], sc[f], 0, 0, 0);

    // c2p: Qstrip(16) @ PKwin(128)^T
    f32x4 cp[8];
#pragma unroll
    for (int jb = 0; jb < 8; jb++) cp[jb] = (f32x4){0.f, 0.f, 0.f, 0.f};
#pragma unroll
    for (int kk = 0; kk < 2; kk++)
#pragma unroll
      for (int jb = 0; jb < 8; jb++) {
        bf16x8 pkf = *(bf16x8*)&PKw[(jb * 16 + li) * 72 + kk * 32 + g * 8];
        cp[jb] = __builtin_amdgcn_mfma_f32_16x16x32_bf16(aq[kk], pkf, cp[jb], 0, 0, 0);
      }
    __syncthreads();  // [C1] all PKw window reads done
    // CtT[j][q] over PKw
#pragma unroll
    for (int jb = 0; jb < 8; jb++) {
      ushort4 a;
      a.x = f2b(cp[jb][0]); a.y = f2b(cp[jb][1]);
      a.z = f2b(cp[jb][2]); a.w = f2b(cp[jb][3]);
      *(ushort4*)&PKw[(jb * 16 + li) * 72 + w * 16 + g * 4] = a;
    }

    // p2c: Kstrip(16) @ PQwin(128)^T  (PQ pre-scaled)
    f32x4 pp[8];
#pragma unroll
    for (int jb = 0; jb < 8; jb++) pp[jb] = (f32x4){0.f, 0.f, 0.f, 0.f};
#pragma unroll
    for (int kk = 0; kk < 2; kk++)
#pragma unroll
      for (int jb = 0; jb < 8; jb++) {
        bf16x8 pqf = *(bf16x8*)&PQw[(jb * 16 + li) * 72 + kk * 32 + g * 8];
        pp[jb] = __builtin_amdgcn_mfma_f32_16x16x32_bf16(ak[kk], pqf, pp[jb], 0, 0, 0);
      }
    __syncthreads();  // [C2] all PQw window reads done
    // PtT[j][k] over PQw
#pragma unroll
    for (int jb = 0; jb < 8; jb++) {
      ushort4 a;
      a.x = f2b(pp[jb][0]); a.y = f2b(pp[jb][1]);
      a.z = f2b(pp[jb][2]); a.w = f2b(pp[jb][3]);
      *(ushort4*)&PQw[(jb * 16 + li) * 72 + w * 16 + g * 4] = a;
    }
    __syncthreads();  // [D] transposed tiles visible

    // combine + online softmax
    float p[4][4];
    float tmax[4] = {-1e30f, -1e30f, -1e30f, -1e30f};
#pragma unroll
    for (int f = 0; f < 4; f++)
#pragma unroll
      for (int r = 0; r < 4; r++) {
        int qi = w * 16 + g * 4 + r;
        int ki = f * 16 + li;
        int sraw = d0 + ki - qi;
        int scl = sraw < 0 ? 0 : (sraw > S2 - 1 ? S2 - 1 : sraw);
        int j = scl - w0;
        float v = sc[f][r] + b2f(PKw[j * 72 + qi]) + b2f(PQw[j * 72 + ki]);
        p[f][r] = v;
        tmax[r] = fmaxf(tmax[r], v);
      }
#pragma unroll
    for (int msk = 1; msk <= 8; msk <<= 1)
#pragma unroll
      for (int r = 0; r < 4; r++) tmax[r] = fmaxf(tmax[r], __shfl_xor(tmax[r], msk));
    float corr[4];
#pragma unroll
    for (int r = 0; r < 4; r++) {
      float mn = fmaxf(mrow[r], tmax[r]);
      corr[r] = __expf(mrow[r] - mn);
      mrow[r] = mn;
      lrow[r] *= corr[r];
    }
#pragma unroll
    for (int n = 0; n < 4; n++)
#pragma unroll
      for (int r = 0; r < 4; r++) o[n][r] *= corr[r];

    __syncthreads();  // [E] all gather reads of CtT/PtT done -> P may overwrite rows 0..63
    float ps[4] = {0.f, 0.f, 0.f, 0.f};
#pragma unroll
    for (int f = 0; f < 4; f++)
#pragma unroll
      for (int r = 0; r < 4; r++) {
        float e = __expf(p[f][r] - mrow[r]);
        ps[r] += e;
        PKw[(w * 16 + g * 4 + r) * 72 + f * 16 + li] = f2b(e);  // P: own wave's rows
      }
#pragma unroll
    for (int msk = 1; msk <= 8; msk <<= 1)
#pragma unroll
      for (int r = 0; r < 4; r++) ps[r] += __shfl_xor(ps[r], msk);
#pragma unroll
    for (int r = 0; r < 4; r++) lrow[r] += ps[r];

    // PV: P rows wave-private (in-wave LDS ordering by compiler); V^T direct from global
#pragma unroll
    for (int kk = 0; kk < 2; kk++) {
      bf16x8 ap = *(bf16x8*)&PKw[(w * 16 + li) * 72 + kk * 32 + g * 8];
#pragma unroll
      for (int n = 0; n < 4; n++) {
        bf16x8 bvf = *(const bf16x8*)&VT[vtb + (long long)(n * 16 + li) * MT + k0 + kk * 32 + g * 8];
        o[n] = __builtin_amdgcn_mfma_f32_16x16x32_bf16(ap, bvf, o[n], 0, 0, 0);
      }
    }
  }

  // epilogue: ctx[b, q, h*64+d] bf16
#pragma unroll
  for (int n = 0; n < 4; n++)
#pragma unroll
    for (int r = 0; r < 4; r++) {
      int q = q0 + w * 16 + g * 4 + r;
      float val = o[n][r] / lrow[r];
      ctxb[((long long)b * TT + q) * DM + h * DKH + n * 16 + li] = f2b(val);
    }
}

// ---------------- host ----------------
extern "C" void kernel_launch(void* const* d_in, const int* in_sizes, int n_in,
                              void* d_out, int out_size, void* d_ws, size_t ws_size,
                              hipStream_t stream) {
  const float* x   = (const float*)d_in[0];
  const float* Wq  = (const float*)d_in[1];
  const float* bq  = (const float*)d_in[2];
  const float* Wk  = (const float*)d_in[3];
  const float* bk  = (const float*)d_in[4];
  const float* Wv  = (const float*)d_in[5];
  const float* bv  = (const float*)d_in[6];
  const float* Wo  = (const float*)d_in[7];
  const float* bo  = (const float*)d_in[8];
  const float* Wpk = (const float*)d_in[9];
  const float* bpk = (const float*)d_in[10];
  const float* Wpq = (const float*)d_in[11];
  const float* bpq = (const float*)d_in[12];
  const float* rel = (const float*)d_in[13];

  uint8_t* ws = (uint8_t*)d_ws;
  size_t off = 0;
  auto alloc = [&](size_t bytes) -> void* {
    void* p = ws + off;
    off += (bytes + 255) & ~(size_t)255;
    return p;
  };
  // NOTE: Wqb/Wkb/Wvb, Qb/Kb/VT, Wpkb/Wpqb, PKb/PQb must each be contiguous (z-strided GEMM)
  unsigned short* xb   = (unsigned short*)alloc((size_t)MT * DM * 2);
  unsigned short* Wqb  = (unsigned short*)alloc((size_t)DM * DM * 2);
  unsigned short* Wkb  = (unsigned short*)alloc((size_t)DM * DM * 2);
  unsigned short* Wvb  = (unsigned short*)alloc((size_t)DM * DM * 2);
  unsigned short* Wob  = (unsigned short*)alloc((size_t)DM * DM * 2);
  unsigned short* Wpkb = (unsigned short*)alloc((size_t)DM * DM * 2);
  unsigned short* Wpqb = (unsigned short*)alloc((size_t)DM * DM * 2);
  unsigned short* reb  = (unsigned short*)alloc((size_t)S2 * DM * 2);
  unsigned short* Qb   = (unsigned short*)alloc((size_t)MT * DM * 2);
  unsigned short* Kb   = (unsigned short*)alloc((size_t)MT * DM * 2);
  unsigned short* VT   = (unsigned short*)alloc((size_t)MT * DM * 2);  // V^T: [h*64+d][b*1024+k]
  unsigned short* PKb  = (unsigned short*)alloc((size_t)S2 * DM * 2);
  unsigned short* PQb  = (unsigned short*)alloc((size_t)S2 * DM * 2);
  unsigned short* ctxb = (unsigned short*)alloc((size_t)MT * DM * 2);

  const float scale = 0.07216878364870323f;  // 1/sqrt(64*3)

  auto cvt = [&](const float* in, unsigned short* outp, int n) {
    int blocks = (n / 4 + 255) / 256;
    if (blocks > 2048) blocks = 2048;
    cvt_kernel<<<dim3(blocks), dim3(256), 0, stream>>>(in, outp, n);
  };
  cvt(x, xb, MT * DM);
  cvt(Wq, Wqb, DM * DM); cvt(Wk, Wkb, DM * DM); cvt(Wv, Wvb, DM * DM);
  cvt(Wo, Wob, DM * DM); cvt(Wpk, Wpkb, DM * DM); cvt(Wpq, Wpqb, DM * DM);
  cvt(rel, reb, S2 * DM);

  // Q/K/V in one launch: z0=Q (alpha=scale, bf16), z1=K (bf16), z2=V (bf16 transposed -> VT)
  gemm_bt<<<dim3(MT / 128, DM / 128, 3), dim3(256), 0, stream>>>(
      xb, Wqb, bq, bk, bv, Qb,
      MT, DM, DM, DM, DM, DM,
      0, (long long)DM * DM, (long long)MT * DM,
      scale, 1.0f, 1.0f, 0x211);

  // PK/PQ in one launch: z0=PK (alpha=1), z1=PQ (alpha=scale)
  gemm_bt<<<dim3(S2 / 128, DM / 128, 2), dim3(256), 0, stream>>>(
      reb, Wpkb, bpk, bpq, nullptr, PKb,
      S2, DM, DM, DM, DM, DM,
      0, (long long)DM * DM, (long long)S2 * DM,
      1.0f, scale, 1.0f, 0x11);

  // fully fused attention
  attn_fused<<<dim3(TT / 64, NH, 4), dim3(256), 0, stream>>>(
      Qb, Kb, VT, PKb, PQb, ctxb);

  // output projection: fp32 out + bias
  gemm_bt<<<dim3(MT / 128, DM / 128, 1), dim3(256), 0, stream>>>(
      ctxb, Wob, bo, nullptr, nullptr, d_out,
      MT, DM, DM, DM, DM, DM,
      0, 0, 0,
      1.0f, 1.0f, 1.0f, 0x0);
}

// Round 2
// 311.464 us; speedup vs baseline: 1.4909x; 1.4909x over previous
//
#include <hip/hip_runtime.h>
#include <stdint.h>

typedef __attribute__((ext_vector_type(8))) short bf16x8;   // 8 bf16 in 4 VGPRs
typedef __attribute__((ext_vector_type(4))) float f32x4;

#define DM   1024
#define TT   1024
#define NH   16
#define DKH  64
#define SPAN 512
#define S2   1024   // 2*SPAN
#define MT   4096   // 4*TT rows

__device__ __forceinline__ unsigned short f2b(float f) {
  unsigned int u = __builtin_bit_cast(unsigned int, f);
  u = (u + 0x7FFFu + ((u >> 16) & 1u)) >> 16;   // RTNE
  return (unsigned short)u;
}
__device__ __forceinline__ float b2f(unsigned short h) {
  unsigned int u = ((unsigned int)h) << 16;
  return __builtin_bit_cast(float, u);
}

// XOR-swizzled LDS index for row-major [R][64]-short tiles (128 B rows).
// 16B chunks permuted within each row: phys_chunk = log_chunk ^ (row & 7).
// All bf16x8 (16B) accesses are chunk-aligned; ushort4/scalar stay inside a chunk.
__device__ __forceinline__ int swz(int row, int col) {
  return (row << 6) + ((((col >> 3) ^ (row & 7)) << 3) | (col & 7));
}

// ---------------- batched f32 -> bf16 convert (one launch for all tensors) ----------------
struct CvtArgs {
  const float* src[8];
  unsigned short* dst[8];
  int n[8];
};
__global__ void cvt_multi(CvtArgs a) {
  const int ti = blockIdx.y;
  const float* __restrict__ in = a.src[ti];
  unsigned short* __restrict__ out = a.dst[ti];
  const int n = a.n[ti];
  int i = (blockIdx.x * blockDim.x + threadIdx.x) * 4;
  int stride = gridDim.x * blockDim.x * 4;
  for (; i < n; i += stride) {
    float4 v = *(const float4*)(in + i);
    ushort4 o;
    o.x = f2b(v.x); o.y = f2b(v.y); o.z = f2b(v.z); o.w = f2b(v.w);
    *(ushort4*)(out + i) = o;
  }
}

// ---------------- multi-z bf16 GEMM: C_z = (A_z(M,K) @ B_z(N,K)^T + bias_z) * alpha_z -------
// mode per z (4 bits in `modes`): 0 = f32 out, 1 = bf16 out, 2 = bf16 TRANSPOSED out C[col*M+row]
__global__ __launch_bounds__(256) void gemm_bt(
    const unsigned short* __restrict__ A, const unsigned short* __restrict__ B,
    const float* __restrict__ bias0, const float* __restrict__ bias1, const float* __restrict__ bias2,
    void* __restrict__ C,
    int M, int N, int K, int lda, int ldb, int ldc,
    long long sA, long long sB, long long sC,
    float a0, float a1, float a2, int modes)
{
  __shared__ unsigned short Al[128 * 72];
  __shared__ unsigned short Bl[128 * 72];
  const int t = threadIdx.x;
  const int w = t >> 6, l = t & 63;
  const int g = l >> 4, li = l & 15;
  const int wr = w >> 1, wc = w & 1;
  const int row0 = blockIdx.x * 128, col0 = blockIdx.y * 128;
  const int z = blockIdx.z;
  const unsigned short* Ab = A + (long long)z * sA;
  const unsigned short* Bb = B + (long long)z * sB;

  f32x4 acc[4][4];
#pragma unroll
  for (int m = 0; m < 4; m++)
#pragma unroll
    for (int n = 0; n < 4; n++) acc[m][n] = (f32x4){0.f, 0.f, 0.f, 0.f};

  for (int k0 = 0; k0 < K; k0 += 64) {
    __syncthreads();
#pragma unroll
    for (int i = 0; i < 4; i++) {
      int c = t + 256 * i;
      int r = c >> 3, c8 = (c & 7) * 8;
      *(bf16x8*)&Al[r * 72 + c8] = *(const bf16x8*)&Ab[(long long)(row0 + r) * lda + k0 + c8];
      *(bf16x8*)&Bl[r * 72 + c8] = *(const bf16x8*)&Bb[(long long)(col0 + r) * ldb + k0 + c8];
    }
    __syncthreads();
#pragma unroll
    for (int kk = 0; kk < 2; kk++) {
      bf16x8 af[4], bfr[4];
#pragma unroll
      for (int m = 0; m < 4; m++) af[m]  = *(bf16x8*)&Al[(wr * 64 + m * 16 + li) * 72 + kk * 32 + g * 8];
#pragma unroll
      for (int n = 0; n < 4; n++) bfr[n] = *(bf16x8*)&Bl[(wc * 64 + n * 16 + li) * 72 + kk * 32 + g * 8];
#pragma unroll
      for (int m = 0; m < 4; m++)
#pragma unroll
        for (int n = 0; n < 4; n++)
          acc[m][n] = __builtin_amdgcn_mfma_f32_16x16x32_bf16(af[m], bfr[n], acc[m][n], 0, 0, 0);
    }
  }

  const float alpha = z == 0 ? a0 : (z == 1 ? a1 : a2);
  const float* bias = z == 0 ? bias0 : (z == 1 ? bias1 : bias2);
  const int mode = (modes >> (4 * z)) & 15;
  const long long zoff = (long long)z * sC;

#pragma unroll
  for (int m = 0; m < 4; m++) {
    int row = row0 + wr * 64 + m * 16 + g * 4;
#pragma unroll
    for (int n = 0; n < 4; n++) {
      int col = col0 + wc * 64 + n * 16 + li;
      float bv = bias ? bias[col] : 0.0f;
      if (mode == 2) {
        // transposed bf16: 4 consecutive rows (k) -> one ushort4 along the fast axis
        ushort4 st;
        st.x = f2b((acc[m][n][0] + bv) * alpha);
        st.y = f2b((acc[m][n][1] + bv) * alpha);
        st.z = f2b((acc[m][n][2] + bv) * alpha);
        st.w = f2b((acc[m][n][3] + bv) * alpha);
        *(ushort4*)&((unsigned short*)C)[zoff + (long long)col * M + row] = st;
      } else {
#pragma unroll
        for (int r = 0; r < 4; r++) {
          float v = (acc[m][n][r] + bv) * alpha;
          long long idx = zoff + (long long)(row + r) * ldc + col;
          if (mode == 1) ((unsigned short*)C)[idx] = f2b(v);
          else           ((float*)C)[idx] = v;
        }
      }
    }
  }
}

// ---------------- fully fused disentangled attention ----------------
// grid (T/64, H, B); block 256 (4 waves x 16 q-rows each).
// score[q,k] = Qs.K + Qs.PK[s] + K.PQs[s], s = clamp(k-q+512, 0, 1023)
// (scale pre-folded into Q and PQ projections)
// LDS (all XOR-swizzled, stride 64, 49152 B -> 3 blocks/CU):
//   Kl  [64][64]   K tile (shared by 4 waves)
//   Vtl [64][64]   V^T tile, staged LINEARLY from pre-transposed VT (no transpose conflicts)
//   PKw [128][64]  PK window -> CtT[j][q] -> P rows 0..63
//   PQw [128][64]  PQ window -> PtT[j][k]
__global__ __launch_bounds__(256, 3) void attn_fused(
    const unsigned short* __restrict__ Qb, const unsigned short* __restrict__ Kb,
    const unsigned short* __restrict__ VT,
    const unsigned short* __restrict__ PKb, const unsigned short* __restrict__ PQb,
    unsigned short* __restrict__ ctxb)
{
  __shared__ unsigned short Kl[64 * 64];
  __shared__ unsigned short Vtl[64 * 64];
  __shared__ unsigned short PKw[128 * 64];
  __shared__ unsigned short PQw[128 * 64];

  const int t = threadIdx.x, w = t >> 6, l = t & 63, g = l >> 4, li = l & 15;
  const int q0 = blockIdx.x * 64;
  const int h = blockIdx.y, b = blockIdx.z;
  const long long qkbase = ((long long)b * TT) * DM + h * DKH;
  const long long vtb = (long long)(h * DKH) * MT + (long long)b * TT;  // + d*MT + k
  const int hbase = h * DKH;

  // Q fragments: direct global, once per block (loop-invariant)
  bf16x8 aq[2];
#pragma unroll
  for (int kk = 0; kk < 2; kk++)
    aq[kk] = *(const bf16x8*)&Qb[qkbase + (long long)(q0 + w * 16 + li) * DM + kk * 32 + g * 8];

  f32x4 o[4];
#pragma unroll
  for (int n = 0; n < 4; n++) o[n] = (f32x4){0.f, 0.f, 0.f, 0.f};
  float mrow[4], lrow[4];
#pragma unroll
  for (int r = 0; r < 4; r++) { mrow[r] = -1e30f; lrow[r] = 0.f; }

  for (int kt = 0; kt < TT / 64; kt++) {
    const int k0 = kt * 64;
    const int d0 = k0 - q0 + SPAN;                       // wave-uniform
    int w0 = d0 - 64;
    w0 = w0 < 0 ? 0 : (w0 > S2 - 128 ? S2 - 128 : w0);

    __syncthreads();  // [A] prev tile's readers of Kl/Vtl/PKw/PQw done
    // stage K tile + V^T tile (V^T staged linearly from pre-transposed global)
#pragma unroll
    for (int i = 0; i < 2; i++) {
      int c = t + 256 * i;
      int r = c >> 3, c8 = (c & 7) * 8;
      *(bf16x8*)&Kl[swz(r, c8)]  = *(const bf16x8*)&Kb[qkbase + (long long)(k0 + r) * DM + c8];
      *(bf16x8*)&Vtl[swz(r, c8)] = *(const bf16x8*)&VT[vtb + (long long)r * MT + k0 + c8];
    }
    // stage PK / PQ windows (128 rows x 64 cols each)
#pragma unroll
    for (int i = 0; i < 4; i++) {
      int c = t + 256 * i;
      int jr = c >> 3, c8 = (c & 7) * 8;
      *(bf16x8*)&PKw[swz(jr, c8)] = *(const bf16x8*)&PKb[(long long)(w0 + jr) * DM + hbase + c8];
      *(bf16x8*)&PQw[swz(jr, c8)] = *(const bf16x8*)&PQb[(long long)(w0 + jr) * DM + hbase + c8];
    }
    __syncthreads();  // [B] staging visible

    // K strip A-fragments (for p2c)
    bf16x8 ak[2];
#pragma unroll
    for (int kk = 0; kk < 2; kk++) ak[kk] = *(bf16x8*)&Kl[swz(w * 16 + li, kk * 32 + g * 8)];

    // QK^T: 16 q-rows x 64 k-cols (Q pre-scaled)
    f32x4 sc[4];
#pragma unroll
    for (int f = 0; f < 4; f++) sc[f] = (f32x4){0.f, 0.f, 0.f, 0.f};
#pragma unroll
    for (int kk = 0; kk < 2; kk++)
#pragma unroll
      for (int f = 0; f < 4; f++) {
        bf16x8 bk = *(bf16x8*)&Kl[swz(f * 16 + li, kk * 32 + g * 8)];
        sc[f] = __builtin_amdgcn_mfma_f32_16x16x32_bf16(aq[kk], bk, sc[f], 0, 0, 0);
      }
    // c2p: Qstrip(16) @ PKwin(128)^T ; p2c: Kstrip(16) @ PQwin(128)^T (PQ pre-scaled)
    f32x4 cp[8], pp[8];
#pragma unroll
    for (int jb = 0; jb < 8; jb++) { cp[jb] = (f32x4){0.f,0.f,0.f,0.f}; pp[jb] = (f32x4){0.f,0.f,0.f,0.f}; }
#pragma unroll
    for (int kk = 0; kk < 2; kk++)
#pragma unroll
      for (int jb = 0; jb < 8; jb++) {
        bf16x8 pkf = *(bf16x8*)&PKw[swz(jb * 16 + li, kk * 32 + g * 8)];
        cp[jb] = __builtin_amdgcn_mfma_f32_16x16x32_bf16(aq[kk], pkf, cp[jb], 0, 0, 0);
      }
#pragma unroll
    for (int kk = 0; kk < 2; kk++)
#pragma unroll
      for (int jb = 0; jb < 8; jb++) {
        bf16x8 pqf = *(bf16x8*)&PQw[swz(jb * 16 + li, kk * 32 + g * 8)];
        pp[jb] = __builtin_amdgcn_mfma_f32_16x16x32_bf16(ak[kk], pqf, pp[jb], 0, 0, 0);
      }
    __syncthreads();  // [C] all window fragment reads done

    // write transposed products over the window buffers:
    // CtT[j][qi] = Qs[qi].PK[w0+j];  PtT[j][ki] = K[ki].PQs[w0+j]
#pragma unroll
    for (int jb = 0; jb < 8; jb++) {
      ushort4 a, p4;
      a.x = f2b(cp[jb][0]); a.y = f2b(cp[jb][1]);
      a.z = f2b(cp[jb][2]); a.w = f2b(cp[jb][3]);
      p4.x = f2b(pp[jb][0]); p4.y = f2b(pp[jb][1]);
      p4.z = f2b(pp[jb][2]); p4.w = f2b(pp[jb][3]);
      *(ushort4*)&PKw[swz(jb * 16 + li, w * 16 + g * 4)] = a;
      *(ushort4*)&PQw[swz(jb * 16 + li, w * 16 + g * 4)] = p4;
    }
    __syncthreads();  // [D] transposed tiles visible

    // combine + online softmax
    float p[4][4];
    float tmax[4] = {-1e30f, -1e30f, -1e30f, -1e30f};
#pragma unroll
    for (int f = 0; f < 4; f++)
#pragma unroll
      for (int r = 0; r < 4; r++) {
        int qi = w * 16 + g * 4 + r;
        int ki = f * 16 + li;
        int sraw = d0 + ki - qi;
        int scl = sraw < 0 ? 0 : (sraw > S2 - 1 ? S2 - 1 : sraw);
        int j = scl - w0;
        float v = sc[f][r] + b2f(PKw[swz(j, qi)]) + b2f(PQw[swz(j, ki)]);
        p[f][r] = v;
        tmax[r] = fmaxf(tmax[r], v);
      }
#pragma unroll
    for (int msk = 1; msk <= 8; msk <<= 1)
#pragma unroll
      for (int r = 0; r < 4; r++) tmax[r] = fmaxf(tmax[r], __shfl_xor(tmax[r], msk));
    float corr[4];
#pragma unroll
    for (int r = 0; r < 4; r++) {
      float mn = fmaxf(mrow[r], tmax[r]);
      corr[r] = __expf(mrow[r] - mn);
      mrow[r] = mn;
      lrow[r] *= corr[r];
    }
#pragma unroll
    for (int n = 0; n < 4; n++)
#pragma unroll
      for (int r = 0; r < 4; r++) o[n][r] *= corr[r];

    __syncthreads();  // [E] all gather reads of CtT/PtT done -> P may overwrite PKw rows 0..63
    float ps[4] = {0.f, 0.f, 0.f, 0.f};
#pragma unroll
    for (int f = 0; f < 4; f++)
#pragma unroll
      for (int r = 0; r < 4; r++) {
        float e = __expf(p[f][r] - mrow[r]);
        ps[r] += e;
        PKw[swz(w * 16 + g * 4 + r, f * 16 + li)] = f2b(e);  // P: own wave's rows
      }
#pragma unroll
    for (int msk = 1; msk <= 8; msk <<= 1)
#pragma unroll
      for (int r = 0; r < 4; r++) ps[r] += __shfl_xor(ps[r], msk);
#pragma unroll
    for (int r = 0; r < 4; r++) lrow[r] += ps[r];

    // PV: P rows wave-private (in-wave LDS ordering by compiler); V^T from LDS
#pragma unroll
    for (int kk = 0; kk < 2; kk++) {
      bf16x8 ap = *(bf16x8*)&PKw[swz(w * 16 + li, kk * 32 + g * 8)];
#pragma unroll
      for (int n = 0; n < 4; n++) {
        bf16x8 bvf = *(bf16x8*)&Vtl[swz(n * 16 + li, kk * 32 + g * 8)];
        o[n] = __builtin_amdgcn_mfma_f32_16x16x32_bf16(ap, bvf, o[n], 0, 0, 0);
      }
    }
  }

  // epilogue: ctx[b, q, h*64+d] bf16
#pragma unroll
  for (int n = 0; n < 4; n++)
#pragma unroll
    for (int r = 0; r < 4; r++) {
      int q = q0 + w * 16 + g * 4 + r;
      float val = o[n][r] / lrow[r];
      ctxb[((long long)b * TT + q) * DM + h * DKH + n * 16 + li] = f2b(val);
    }
}

// ---------------- host ----------------
extern "C" void kernel_launch(void* const* d_in, const int* in_sizes, int n_in,
                              void* d_out, int out_size, void* d_ws, size_t ws_size,
                              hipStream_t stream) {
  const float* x   = (const float*)d_in[0];
  const float* Wq  = (const float*)d_in[1];
  const float* bq  = (const float*)d_in[2];
  const float* Wk  = (const float*)d_in[3];
  const float* bk  = (const float*)d_in[4];
  const float* Wv  = (const float*)d_in[5];
  const float* bv  = (const float*)d_in[6];
  const float* Wo  = (const float*)d_in[7];
  const float* bo  = (const float*)d_in[8];
  const float* Wpk = (const float*)d_in[9];
  const float* bpk = (const float*)d_in[10];
  const float* Wpq = (const float*)d_in[11];
  const float* bpq = (const float*)d_in[12];
  const float* rel = (const float*)d_in[13];

  uint8_t* ws = (uint8_t*)d_ws;
  size_t off = 0;
  auto alloc = [&](size_t bytes) -> void* {
    void* p = ws + off;
    off += (bytes + 255) & ~(size_t)255;
    return p;
  };
  // NOTE: Wqb/Wkb/Wvb, Qb/Kb/VT, Wpkb/Wpqb, PKb/PQb must each be contiguous (z-strided GEMM)
  unsigned short* xb   = (unsigned short*)alloc((size_t)MT * DM * 2);
  unsigned short* Wqb  = (unsigned short*)alloc((size_t)DM * DM * 2);
  unsigned short* Wkb  = (unsigned short*)alloc((size_t)DM * DM * 2);
  unsigned short* Wvb  = (unsigned short*)alloc((size_t)DM * DM * 2);
  unsigned short* Wob  = (unsigned short*)alloc((size_t)DM * DM * 2);
  unsigned short* Wpkb = (unsigned short*)alloc((size_t)DM * DM * 2);
  unsigned short* Wpqb = (unsigned short*)alloc((size_t)DM * DM * 2);
  unsigned short* reb  = (unsigned short*)alloc((size_t)S2 * DM * 2);
  unsigned short* Qb   = (unsigned short*)alloc((size_t)MT * DM * 2);
  unsigned short* Kb   = (unsigned short*)alloc((size_t)MT * DM * 2);
  unsigned short* VT   = (unsigned short*)alloc((size_t)MT * DM * 2);  // V^T: [h*64+d][b*1024+k]
  unsigned short* PKb  = (unsigned short*)alloc((size_t)S2 * DM * 2);
  unsigned short* PQb  = (unsigned short*)alloc((size_t)S2 * DM * 2);
  unsigned short* ctxb = (unsigned short*)alloc((size_t)MT * DM * 2);

  const float scale = 0.07216878364870323f;  // 1/sqrt(64*3)

  // one batched convert launch for all 8 fp32 tensors
  CvtArgs ca;
  ca.src[0] = x;   ca.dst[0] = xb;   ca.n[0] = MT * DM;
  ca.src[1] = Wq;  ca.dst[1] = Wqb;  ca.n[1] = DM * DM;
  ca.src[2] = Wk;  ca.dst[2] = Wkb;  ca.n[2] = DM * DM;
  ca.src[3] = Wv;  ca.dst[3] = Wvb;  ca.n[3] = DM * DM;
  ca.src[4] = Wo;  ca.dst[4] = Wob;  ca.n[4] = DM * DM;
  ca.src[5] = Wpk; ca.dst[5] = Wpkb; ca.n[5] = DM * DM;
  ca.src[6] = Wpq; ca.dst[6] = Wpqb; ca.n[6] = DM * DM;
  ca.src[7] = rel; ca.dst[7] = reb;  ca.n[7] = S2 * DM;
  cvt_multi<<<dim3(1024, 8), dim3(256), 0, stream>>>(ca);

  // Q/K/V in one launch: z0=Q (alpha=scale, bf16), z1=K (bf16), z2=V (bf16 transposed -> VT)
  gemm_bt<<<dim3(MT / 128, DM / 128, 3), dim3(256), 0, stream>>>(
      xb, Wqb, bq, bk, bv, Qb,
      MT, DM, DM, DM, DM, DM,
      0, (long long)DM * DM, (long long)MT * DM,
      scale, 1.0f, 1.0f, 0x211);

  // PK/PQ in one launch: z0=PK (alpha=1), z1=PQ (alpha=scale)
  gemm_bt<<<dim3(S2 / 128, DM / 128, 2), dim3(256), 0, stream>>>(
      reb, Wpkb, bpk, bpq, nullptr, PKb,
      S2, DM, DM, DM, DM, DM,
      0, (long long)DM * DM, (long long)S2 * DM,
      1.0f, scale, 1.0f, 0x11);

  // fully fused attention
  attn_fused<<<dim3(TT / 64, NH, 4), dim3(256), 0, stream>>>(
      Qb, Kb, VT, PKb, PQb, ctxb);

  // output projection: fp32 out + bias
  gemm_bt<<<dim3(MT / 128, DM / 128, 1), dim3(256), 0, stream>>>(
      ctxb, Wob, bo, nullptr, nullptr, d_out,
      MT, DM, DM, DM, DM, DM,
      0, 0, 0,
      1.0f, 1.0f, 1.0f, 0x0);
}

// Round 3
// 262.031 us; speedup vs baseline: 1.7722x; 1.1887x over previous
//
#include <hip/hip_runtime.h>
#include <stdint.h>

typedef __attribute__((ext_vector_type(8))) short bf16x8;   // 8 bf16 in 4 VGPRs
typedef __attribute__((ext_vector_type(4))) float f32x4;

#define DM   1024
#define TT   1024
#define NH   16
#define DKH  64
#define SPAN 512
#define S2   1024   // 2*SPAN
#define MT   4096   // 4*TT rows

__device__ __forceinline__ unsigned short f2b(float f) {
  unsigned int u = __builtin_bit_cast(unsigned int, f);
  u = (u + 0x7FFFu + ((u >> 16) & 1u)) >> 16;   // RTNE
  return (unsigned short)u;
}
__device__ __forceinline__ float b2f(unsigned short h) {
  unsigned int u = ((unsigned int)h) << 16;
  return __builtin_bit_cast(float, u);
}

// XOR-swizzled LDS index for row-major [R][64]-short tiles (128 B rows).
// 16B chunks permuted within each row: phys_chunk = log_chunk ^ (row & 7).
// All bf16x8 (16B) accesses are chunk-aligned; ushort4/scalar stay inside a chunk.
__device__ __forceinline__ int swz(int row, int col) {
  return (row << 6) + ((((col >> 3) ^ (row & 7)) << 3) | (col & 7));
}

// ---------------- batched f32 -> bf16 convert (one launch for all tensors) ----------------
struct CvtArgs {
  const float* src[8];
  unsigned short* dst[8];
  int n[8];
};
__global__ void cvt_multi(CvtArgs a) {
  const int ti = blockIdx.y;
  const float* __restrict__ in = a.src[ti];
  unsigned short* __restrict__ out = a.dst[ti];
  const int n = a.n[ti];
  int i = (blockIdx.x * blockDim.x + threadIdx.x) * 4;
  int stride = gridDim.x * blockDim.x * 4;
  for (; i < n; i += stride) {
    float4 v = *(const float4*)(in + i);
    ushort4 o;
    o.x = f2b(v.x); o.y = f2b(v.y); o.z = f2b(v.z); o.w = f2b(v.w);
    *(ushort4*)(out + i) = o;
  }
}

// ---------------- multi-z bf16 GEMM: C_z = (A_z(M,K) @ B_z(N,K)^T + bias_z) * alpha_z -------
// mode per z (4 bits in `modes`): 0 = f32 out, 1 = bf16 out, 2 = bf16 TRANSPOSED out C[col*M+row]
__global__ __launch_bounds__(256) void gemm_bt(
    const unsigned short* __restrict__ A, const unsigned short* __restrict__ B,
    const float* __restrict__ bias0, const float* __restrict__ bias1, const float* __restrict__ bias2,
    void* __restrict__ C,
    int M, int N, int K, int lda, int ldb, int ldc,
    long long sA, long long sB, long long sC,
    float a0, float a1, float a2, int modes)
{
  __shared__ unsigned short Al[128 * 72];
  __shared__ unsigned short Bl[128 * 72];
  const int t = threadIdx.x;
  const int w = t >> 6, l = t & 63;
  const int g = l >> 4, li = l & 15;
  const int wr = w >> 1, wc = w & 1;
  const int row0 = blockIdx.x * 128, col0 = blockIdx.y * 128;
  const int z = blockIdx.z;
  const unsigned short* Ab = A + (long long)z * sA;
  const unsigned short* Bb = B + (long long)z * sB;

  f32x4 acc[4][4];
#pragma unroll
  for (int m = 0; m < 4; m++)
#pragma unroll
    for (int n = 0; n < 4; n++) acc[m][n] = (f32x4){0.f, 0.f, 0.f, 0.f};

  for (int k0 = 0; k0 < K; k0 += 64) {
    __syncthreads();
#pragma unroll
    for (int i = 0; i < 4; i++) {
      int c = t + 256 * i;
      int r = c >> 3, c8 = (c & 7) * 8;
      *(bf16x8*)&Al[r * 72 + c8] = *(const bf16x8*)&Ab[(long long)(row0 + r) * lda + k0 + c8];
      *(bf16x8*)&Bl[r * 72 + c8] = *(const bf16x8*)&Bb[(long long)(col0 + r) * ldb + k0 + c8];
    }
    __syncthreads();
#pragma unroll
    for (int kk = 0; kk < 2; kk++) {
      bf16x8 af[4], bfr[4];
#pragma unroll
      for (int m = 0; m < 4; m++) af[m]  = *(bf16x8*)&Al[(wr * 64 + m * 16 + li) * 72 + kk * 32 + g * 8];
#pragma unroll
      for (int n = 0; n < 4; n++) bfr[n] = *(bf16x8*)&Bl[(wc * 64 + n * 16 + li) * 72 + kk * 32 + g * 8];
#pragma unroll
      for (int m = 0; m < 4; m++)
#pragma unroll
        for (int n = 0; n < 4; n++)
          acc[m][n] = __builtin_amdgcn_mfma_f32_16x16x32_bf16(af[m], bfr[n], acc[m][n], 0, 0, 0);
    }
  }

  const float alpha = z == 0 ? a0 : (z == 1 ? a1 : a2);
  const float* bias = z == 0 ? bias0 : (z == 1 ? bias1 : bias2);
  const int mode = (modes >> (4 * z)) & 15;
  const long long zoff = (long long)z * sC;

#pragma unroll
  for (int m = 0; m < 4; m++) {
    int row = row0 + wr * 64 + m * 16 + g * 4;
#pragma unroll
    for (int n = 0; n < 4; n++) {
      int col = col0 + wc * 64 + n * 16 + li;
      float bv = bias ? bias[col] : 0.0f;
      if (mode == 2) {
        ushort4 st;
        st.x = f2b((acc[m][n][0] + bv) * alpha);
        st.y = f2b((acc[m][n][1] + bv) * alpha);
        st.z = f2b((acc[m][n][2] + bv) * alpha);
        st.w = f2b((acc[m][n][3] + bv) * alpha);
        *(ushort4*)&((unsigned short*)C)[zoff + (long long)col * M + row] = st;
      } else {
#pragma unroll
        for (int r = 0; r < 4; r++) {
          float v = (acc[m][n][r] + bv) * alpha;
          long long idx = zoff + (long long)(row + r) * ldc + col;
          if (mode == 1) ((unsigned short*)C)[idx] = f2b(v);
          else           ((float*)C)[idx] = v;
        }
      }
    }
  }
}

// ---------------- fully fused disentangled attention ----------------
// grid 1024 (flat, XCD-swizzled); block 256 (4 waves x 16 q-rows each).
// score[q,k] = Qs.K + Qs.PK[s] + K.PQs[s], s = clamp(k-q+512, 0, 1023)
// Ct is a PERSISTENT circular buffer over absolute s (slot = s & 127):
// CtT[slot][q] = Qs[q].PK[s] depends only on (s, q-block) -> computed once per s
// (64 new rows per slide; window start w0 moves in {0,+64} steps, both mult. of 64).
// Ct columns are wave-private (wave w writes & gathers cols [16w,16w+16)).
// Pt depends on the K-tile -> recomputed per tile, but each wave only needs rows
// s in [d0+16w-63, d0+16w+15] (79 rows) for its columns -> 6 predicated jb blocks.
__global__ __launch_bounds__(256, 3) void attn_fused(
    const unsigned short* __restrict__ Qb, const unsigned short* __restrict__ Kb,
    const unsigned short* __restrict__ VT,
    const unsigned short* __restrict__ PKb, const unsigned short* __restrict__ PQb,
    unsigned short* __restrict__ ctxb)
{
  __shared__ unsigned short Kl[64 * 64];   // K tile; P tile after [D]
  __shared__ unsigned short Vtl[64 * 64];  // V^T tile
  __shared__ unsigned short Ct[128 * 64];  // circular CtT[s&127][q] (raw PK during slide)
  __shared__ unsigned short Pq[128 * 64];  // raw PQ window -> PtT[j][k] (per tile)

  const int t = threadIdx.x, w = t >> 6, l = t & 63, g = l >> 4, li = l & 15;
  // XCD-aware role swizzle: dispatch id -> role so each XCD gets 128 contiguous roles
  const int bid = blockIdx.x;
  const int role = (bid & 7) * 128 + (bid >> 3);
  const int q0 = (role & 15) * 64;
  const int h = (role >> 4) & 15;
  const int b = role >> 8;
  const long long qkbase = ((long long)b * TT) * DM + h * DKH;
  const long long vtb = (long long)(h * DKH) * MT + (long long)b * TT;  // + d*MT + k
  const int hbase = h * DKH;

  // Q fragments: direct global, once per block (loop-invariant)
  bf16x8 aq[2];
#pragma unroll
  for (int kk = 0; kk < 2; kk++)
    aq[kk] = *(const bf16x8*)&Qb[qkbase + (long long)(q0 + w * 16 + li) * DM + kk * 32 + g * 8];

  // ---- prologue: fill circular Ct for the kt=0 window ----
  int w0 = SPAN - q0 - 64;
  w0 = w0 < 0 ? 0 : (w0 > S2 - 128 ? S2 - 128 : w0);
#pragma unroll
  for (int i = 0; i < 4; i++) {
    int c = t + 256 * i;
    int jr = c >> 3, c8 = (c & 7) * 8;
    *(bf16x8*)&Ct[swz((w0 + jr) & 127, c8)] =
        *(const bf16x8*)&PKb[(long long)(w0 + jr) * DM + hbase + c8];
  }
  __syncthreads();
  {
    f32x4 cp[8];
#pragma unroll
    for (int jb = 0; jb < 8; jb++) cp[jb] = (f32x4){0.f, 0.f, 0.f, 0.f};
    __builtin_amdgcn_s_setprio(1);
#pragma unroll
    for (int kk = 0; kk < 2; kk++)
#pragma unroll
      for (int jb = 0; jb < 8; jb++) {
        bf16x8 pkf = *(bf16x8*)&Ct[swz(jb * 16 + li, kk * 32 + g * 8)];
        cp[jb] = __builtin_amdgcn_mfma_f32_16x16x32_bf16(aq[kk], pkf, cp[jb], 0, 0, 0);
      }
    __builtin_amdgcn_s_setprio(0);
    __syncthreads();  // all raw reads done before overwrite
#pragma unroll
    for (int jb = 0; jb < 8; jb++) {
      ushort4 a;
      a.x = f2b(cp[jb][0]); a.y = f2b(cp[jb][1]);
      a.z = f2b(cp[jb][2]); a.w = f2b(cp[jb][3]);
      *(ushort4*)&Ct[swz(jb * 16 + li, w * 16 + g * 4)] = a;   // own-wave cols only
    }
  }

  f32x4 o[4];
#pragma unroll
  for (int n = 0; n < 4; n++) o[n] = (f32x4){0.f, 0.f, 0.f, 0.f};
  float mrow[4], lrow[4];
#pragma unroll
  for (int r = 0; r < 4; r++) { mrow[r] = -1e30f; lrow[r] = 0.f; }

  for (int kt = 0; kt < TT / 64; kt++) {
    const int k0 = kt * 64;
    const int d0 = k0 - q0 + SPAN;                       // block-uniform
    int w0n = d0 - 64;
    w0n = w0n < 0 ? 0 : (w0n > S2 - 128 ? S2 - 128 : w0n);
    const bool slide = (w0n != w0);                      // step is always exactly +64
    const int sb = w0 & 127;                             // slots replaced on slide (0 or 64)
    const int newrow0 = w0 + 128;                        // abs first new row on slide
    w0 = w0n;

    __syncthreads();  // [A] prev tile readers of Kl/Vtl/Ct/Pq done
    // stage K tile + V^T tile
#pragma unroll
    for (int i = 0; i < 2; i++) {
      int c = t + 256 * i;
      int r = c >> 3, c8 = (c & 7) * 8;
      *(bf16x8*)&Kl[swz(r, c8)]  = *(const bf16x8*)&Kb[qkbase + (long long)(k0 + r) * DM + c8];
      *(bf16x8*)&Vtl[swz(r, c8)] = *(const bf16x8*)&VT[vtb + (long long)r * MT + k0 + c8];
    }
    // stage raw PQ window (every tile; overwritten by PtT)
#pragma unroll
    for (int i = 0; i < 4; i++) {
      int c = t + 256 * i;
      int jr = c >> 3, c8 = (c & 7) * 8;
      *(bf16x8*)&Pq[swz(jr, c8)] = *(const bf16x8*)&PQb[(long long)(w0 + jr) * DM + hbase + c8];
    }
    // stage 64 new raw PK rows on slide (into recycled Ct slots)
    if (slide) {
#pragma unroll
      for (int i = 0; i < 2; i++) {
        int c = t + 256 * i;
        int jr = c >> 3, c8 = (c & 7) * 8;
        *(bf16x8*)&Ct[swz(sb + jr, c8)] =
            *(const bf16x8*)&PKb[(long long)(newrow0 + jr) * DM + hbase + c8];
      }
    }
    __syncthreads();  // [B] staging visible

    // K strip A-fragments (for p2c)
    bf16x8 ak[2];
#pragma unroll
    for (int kk = 0; kk < 2; kk++) ak[kk] = *(bf16x8*)&Kl[swz(w * 16 + li, kk * 32 + g * 8)];

    __builtin_amdgcn_s_setprio(1);
    // QK^T: 16 q-rows x 64 k-cols (Q pre-scaled)
    f32x4 sc[4];
#pragma unroll
    for (int f = 0; f < 4; f++) sc[f] = (f32x4){0.f, 0.f, 0.f, 0.f};
#pragma unroll
    for (int kk = 0; kk < 2; kk++)
#pragma unroll
      for (int f = 0; f < 4; f++) {
        bf16x8 bk = *(bf16x8*)&Kl[swz(f * 16 + li, kk * 32 + g * 8)];
        sc[f] = __builtin_amdgcn_mfma_f32_16x16x32_bf16(aq[kk], bk, sc[f], 0, 0, 0);
      }
    // c2p for the 64 new slots only (slide tiles)
    f32x4 cp2[4];
#pragma unroll
    for (int jb = 0; jb < 4; jb++) cp2[jb] = (f32x4){0.f, 0.f, 0.f, 0.f};
    if (slide) {
#pragma unroll
      for (int kk = 0; kk < 2; kk++)
#pragma unroll
        for (int jb = 0; jb < 4; jb++) {
          bf16x8 pkf = *(bf16x8*)&Ct[swz(sb + jb * 16 + li, kk * 32 + g * 8)];
          cp2[jb] = __builtin_amdgcn_mfma_f32_16x16x32_bf16(aq[kk], pkf, cp2[jb], 0, 0, 0);
        }
    }
    // p2c restricted to this wave's needed rows: s in [d0+16w-63, d0+16w+15]
    int loA = d0 + w * 16 - 63; loA = loA < w0 ? w0 : loA;
    int hiA = d0 + w * 16 + 15; hiA = hiA > w0 + 127 ? w0 + 127 : hiA;
    const int jb_lo = (loA - w0) >> 4;
    const int jb_n  = ((hiA - w0) >> 4) - jb_lo;   // 0..5 inclusive extra blocks
    f32x4 pp[6];
#pragma unroll
    for (int u = 0; u < 6; u++) pp[u] = (f32x4){0.f, 0.f, 0.f, 0.f};
#pragma unroll
    for (int kk = 0; kk < 2; kk++)
#pragma unroll
      for (int u = 0; u < 6; u++)
        if (u <= jb_n) {
          bf16x8 pqf = *(bf16x8*)&Pq[swz((jb_lo + u) * 16 + li, kk * 32 + g * 8)];
          pp[u] = __builtin_amdgcn_mfma_f32_16x16x32_bf16(ak[kk], pqf, pp[u], 0, 0, 0);
        }
    __builtin_amdgcn_s_setprio(0);
    __syncthreads();  // [C] all raw window reads + Kl fragment reads done

    // overwrite with transposed products (own-wave columns)
    if (slide) {
#pragma unroll
      for (int jb = 0; jb < 4; jb++) {
        ushort4 a;
        a.x = f2b(cp2[jb][0]); a.y = f2b(cp2[jb][1]);
        a.z = f2b(cp2[jb][2]); a.w = f2b(cp2[jb][3]);
        *(ushort4*)&Ct[swz(sb + jb * 16 + li, w * 16 + g * 4)] = a;
      }
    }
#pragma unroll
    for (int u = 0; u < 6; u++)
      if (u <= jb_n) {
        ushort4 a;
        a.x = f2b(pp[u][0]); a.y = f2b(pp[u][1]);
        a.z = f2b(pp[u][2]); a.w = f2b(pp[u][3]);
        *(ushort4*)&Pq[swz((jb_lo + u) * 16 + li, w * 16 + g * 4)] = a;
      }
    __syncthreads();  // [D] PtT visible cross-wave (Ct gather is wave-private)

    // combine + online softmax
    float p[4][4];
    float tmax[4] = {-1e30f, -1e30f, -1e30f, -1e30f};
#pragma unroll
    for (int f = 0; f < 4; f++)
#pragma unroll
      for (int r = 0; r < 4; r++) {
        int qi = w * 16 + g * 4 + r;
        int ki = f * 16 + li;
        int sraw = d0 + ki - qi;
        int scl = sraw < 0 ? 0 : (sraw > S2 - 1 ? S2 - 1 : sraw);
        int slot = scl & 127;
        int j = scl - w0;
        float v = sc[f][r] + b2f(Ct[swz(slot, qi)]) + b2f(Pq[swz(j, ki)]);
        p[f][r] = v;
        tmax[r] = fmaxf(tmax[r], v);
      }
#pragma unroll
    for (int msk = 1; msk <= 8; msk <<= 1)
#pragma unroll
      for (int r = 0; r < 4; r++) tmax[r] = fmaxf(tmax[r], __shfl_xor(tmax[r], msk));
    float corr[4];
#pragma unroll
    for (int r = 0; r < 4; r++) {
      float mn = fmaxf(mrow[r], tmax[r]);
      corr[r] = __expf(mrow[r] - mn);
      mrow[r] = mn;
      lrow[r] *= corr[r];
    }
#pragma unroll
    for (int n = 0; n < 4; n++)
#pragma unroll
      for (int r = 0; r < 4; r++) o[n][r] *= corr[r];

    float ps[4] = {0.f, 0.f, 0.f, 0.f};
#pragma unroll
    for (int f = 0; f < 4; f++)
#pragma unroll
      for (int r = 0; r < 4; r++) {
        float e = __expf(p[f][r] - mrow[r]);
        ps[r] += e;
        Kl[swz(w * 16 + g * 4 + r, f * 16 + li)] = f2b(e);  // P over Kl: own wave's rows
      }
#pragma unroll
    for (int msk = 1; msk <= 8; msk <<= 1)
#pragma unroll
      for (int r = 0; r < 4; r++) ps[r] += __shfl_xor(ps[r], msk);
#pragma unroll
    for (int r = 0; r < 4; r++) lrow[r] += ps[r];

    // PV: P rows wave-private (in-wave LDS ordering by compiler); V^T from LDS
    __builtin_amdgcn_s_setprio(1);
#pragma unroll
    for (int kk = 0; kk < 2; kk++) {
      bf16x8 ap = *(bf16x8*)&Kl[swz(w * 16 + li, kk * 32 + g * 8)];
#pragma unroll
      for (int n = 0; n < 4; n++) {
        bf16x8 bvf = *(bf16x8*)&Vtl[swz(n * 16 + li, kk * 32 + g * 8)];
        o[n] = __builtin_amdgcn_mfma_f32_16x16x32_bf16(ap, bvf, o[n], 0, 0, 0);
      }
    }
    __builtin_amdgcn_s_setprio(0);
  }

  // epilogue: ctx[b, q, h*64+d] bf16
#pragma unroll
  for (int n = 0; n < 4; n++)
#pragma unroll
    for (int r = 0; r < 4; r++) {
      int q = q0 + w * 16 + g * 4 + r;
      float val = o[n][r] / lrow[r];
      ctxb[((long long)b * TT + q) * DM + h * DKH + n * 16 + li] = f2b(val);
    }
}

// ---------------- host ----------------
extern "C" void kernel_launch(void* const* d_in, const int* in_sizes, int n_in,
                              void* d_out, int out_size, void* d_ws, size_t ws_size,
                              hipStream_t stream) {
  const float* x   = (const float*)d_in[0];
  const float* Wq  = (const float*)d_in[1];
  const float* bq  = (const float*)d_in[2];
  const float* Wk  = (const float*)d_in[3];
  const float* bk  = (const float*)d_in[4];
  const float* Wv  = (const float*)d_in[5];
  const float* bv  = (const float*)d_in[6];
  const float* Wo  = (const float*)d_in[7];
  const float* bo  = (const float*)d_in[8];
  const float* Wpk = (const float*)d_in[9];
  const float* bpk = (const float*)d_in[10];
  const float* Wpq = (const float*)d_in[11];
  const float* bpq = (const float*)d_in[12];
  const float* rel = (const float*)d_in[13];

  uint8_t* ws = (uint8_t*)d_ws;
  size_t off = 0;
  auto alloc = [&](size_t bytes) -> void* {
    void* p = ws + off;
    off += (bytes + 255) & ~(size_t)255;
    return p;
  };
  // NOTE: Wqb/Wkb/Wvb, Qb/Kb/VT, Wpkb/Wpqb, PKb/PQb must each be contiguous (z-strided GEMM)
  unsigned short* xb   = (unsigned short*)alloc((size_t)MT * DM * 2);
  unsigned short* Wqb  = (unsigned short*)alloc((size_t)DM * DM * 2);
  unsigned short* Wkb  = (unsigned short*)alloc((size_t)DM * DM * 2);
  unsigned short* Wvb  = (unsigned short*)alloc((size_t)DM * DM * 2);
  unsigned short* Wob  = (unsigned short*)alloc((size_t)DM * DM * 2);
  unsigned short* Wpkb = (unsigned short*)alloc((size_t)DM * DM * 2);
  unsigned short* Wpqb = (unsigned short*)alloc((size_t)DM * DM * 2);
  unsigned short* reb  = (unsigned short*)alloc((size_t)S2 * DM * 2);
  unsigned short* Qb   = (unsigned short*)alloc((size_t)MT * DM * 2);
  unsigned short* Kb   = (unsigned short*)alloc((size_t)MT * DM * 2);
  unsigned short* VT   = (unsigned short*)alloc((size_t)MT * DM * 2);  // V^T: [h*64+d][b*1024+k]
  unsigned short* PKb  = (unsigned short*)alloc((size_t)S2 * DM * 2);
  unsigned short* PQb  = (unsigned short*)alloc((size_t)S2 * DM * 2);
  unsigned short* ctxb = (unsigned short*)alloc((size_t)MT * DM * 2);

  const float scale = 0.07216878364870323f;  // 1/sqrt(64*3)

  // one batched convert launch for all 8 fp32 tensors
  CvtArgs ca;
  ca.src[0] = x;   ca.dst[0] = xb;   ca.n[0] = MT * DM;
  ca.src[1] = Wq;  ca.dst[1] = Wqb;  ca.n[1] = DM * DM;
  ca.src[2] = Wk;  ca.dst[2] = Wkb;  ca.n[2] = DM * DM;
  ca.src[3] = Wv;  ca.dst[3] = Wvb;  ca.n[3] = DM * DM;
  ca.src[4] = Wo;  ca.dst[4] = Wob;  ca.n[4] = DM * DM;
  ca.src[5] = Wpk; ca.dst[5] = Wpkb; ca.n[5] = DM * DM;
  ca.src[6] = Wpq; ca.dst[6] = Wpqb; ca.n[6] = DM * DM;
  ca.src[7] = rel; ca.dst[7] = reb;  ca.n[7] = S2 * DM;
  cvt_multi<<<dim3(1024, 8), dim3(256), 0, stream>>>(ca);

  // Q/K/V in one launch: z0=Q (alpha=scale, bf16), z1=K (bf16), z2=V (bf16 transposed -> VT)
  gemm_bt<<<dim3(MT / 128, DM / 128, 3), dim3(256), 0, stream>>>(
      xb, Wqb, bq, bk, bv, Qb,
      MT, DM, DM, DM, DM, DM,
      0, (long long)DM * DM, (long long)MT * DM,
      scale, 1.0f, 1.0f, 0x211);

  // PK/PQ in one launch: z0=PK (alpha=1), z1=PQ (alpha=scale)
  gemm_bt<<<dim3(S2 / 128, DM / 128, 2), dim3(256), 0, stream>>>(
      reb, Wpkb, bpk, bpq, nullptr, PKb,
      S2, DM, DM, DM, DM, DM,
      0, (long long)DM * DM, (long long)S2 * DM,
      1.0f, scale, 1.0f, 0x11);

  // fully fused attention (flat grid, XCD-swizzled roles)
  attn_fused<<<dim3(1024), dim3(256), 0, stream>>>(
      Qb, Kb, VT, PKb, PQb, ctxb);

  // output projection: fp32 out + bias
  gemm_bt<<<dim3(MT / 128, DM / 128, 1), dim3(256), 0, stream>>>(
      ctxb, Wob, bo, nullptr, nullptr, d_out,
      MT, DM, DM, DM, DM, DM,
      0, 0, 0,
      1.0f, 1.0f, 1.0f, 0x0);
}